// Round 6
// baseline (1994.999 us; speedup 1.0000x reference)
//
#include <hip/hip_runtime.h>

typedef unsigned short u16;
typedef unsigned int u32;
typedef unsigned long long u64;
typedef __attribute__((ext_vector_type(8))) short short8;
typedef __attribute__((ext_vector_type(4))) float f32x4;
typedef __attribute__((ext_vector_type(4))) u32 u32x4;
typedef __attribute__((ext_vector_type(2))) u32 u32x2;

#define RN_ 8388608  // B*T*H
#define MFMA16(a, b, c) __builtin_amdgcn_mfma_f32_16x16x32_bf16(a, b, c, 0, 0, 0)

__device__ __forceinline__ u16 f2bf(float f) {
  union { float f; u32 u; } v; v.f = f;
  u32 r = v.u + 0x7fffu + ((v.u >> 16) & 1u);  // RNE (inputs finite)
  return (u16)(r >> 16);
}
__device__ __forceinline__ float bf2f(u16 h) {
  union { u32 u; float f; } v; v.u = ((u32)h) << 16;
  return v.f;
}
__device__ __forceinline__ u32 pk2(float a, float b) {
  return (u32)f2bf(a) | ((u32)f2bf(b) << 16);
}
// scan column ordering: R = blk*32 + u_local*4 + gate -> original g = gate*1024 + blk*8 + u_local
__device__ __forceinline__ int permcol(int R) {
  return (R & 3) * 1024 + ((R >> 5) << 3) + ((R >> 2) & 7);
}
__device__ __forceinline__ float sigm(float x) { return 1.f / (1.f + __expf(-x)); }
__device__ __forceinline__ float tanh_(float x) {
  float e = __expf(2.f * x);
  return 1.f - 2.f / (e + 1.f);
}

// -------- transpose + convert + permute: four [4096][1024] bf16 buffers --------
__global__ __launch_bounds__(256) void transpose_convert(
    const float* __restrict__ Wx, const float* __restrict__ Wh,
    u16* __restrict__ WxT1, u16* __restrict__ WxT2,
    u16* __restrict__ WhT1, u16* __restrict__ WhT2) {
  __shared__ float lds[64][65];
  const int bid = blockIdx.x, tid = threadIdx.x;
  const int sel = bid >> 10;
  const int tile = bid & 1023;
  const int kt = tile & 15, rt = tile >> 4;  // 16 k-tiles x 64 R-tiles
  const float* src;
  u16* dst;
  if (sel == 0)      { src = Wx;                       dst = WxT1; }
  else if (sel == 1) { src = Wx + (size_t)1024 * 4096; dst = WxT2; }
  else if (sel == 2) { src = Wh;                       dst = WhT1; }
  else               { src = Wh + (size_t)1024 * 4096; dst = WhT2; }
#pragma unroll
  for (int ii = 0; ii < 16; ++ii) {
    int idx = ii * 256 + tid;
    int r = idx >> 6, c = idx & 63;
    int run = c >> 3, u = c & 7;
    int blkLoc = run >> 2, gate = run & 3;
    int g = gate * 1024 + (rt * 2 + blkLoc) * 8 + u;
    lds[r][blkLoc * 32 + u * 4 + gate] = src[(size_t)(kt * 64 + r) * 4096 + g];
  }
  __syncthreads();
#pragma unroll
  for (int ii = 0; ii < 16; ++ii) {
    int idx = ii * 256 + tid;
    int rw = idx >> 6, cw = idx & 63;
    dst[(size_t)(rt * 64 + rw) * 1024 + kt * 64 + cw] = f2bf(lds[cw][rw]);
  }
}

// -------- chunked GEMM group (persistent): 128 blocks, 16 chunks of 512 rows --------
// IS2=0: A = x (f32, rows remapped b*256+t), out -> xp1ring, gate: ring reuse vs scan1.
// IS2=1: A = out1t (bf16, CACHED + per-chunk acquire fence), gate: scan1 chunk done
//        + scan2 ring reuse.
// C rows are t-major (r = t*32+b), cols permuted; bias added here. C stores uncached.
template <int IS2>
__device__ void gemm_grp(char* smem, int gb,
    const float* __restrict__ Af32, const u16* __restrict__ Abf,
    const u16* __restrict__ Bt, const float* __restrict__ bias,
    u16* __restrict__ Cring, const int* flags, int* gdone) {
  u16* As = (u16*)smem;
  u16* Bs = (u16*)(smem + 16384);
  const int tid = threadIdx.x;
  const int lane = tid & 63, w = tid >> 6;
  const int wm = w >> 1, wn = w & 1;
  const int l15 = lane & 15, lq = lane >> 4;
  const int srow = tid >> 2, qd = tid & 3;
  const int mg = gb >> 5, ng = gb & 31;
  const u32 rsw = (u32)((l15 & 7) << 4);

  for (int c = 0; c < 16; ++c) {
    // ---- gate ----
    if (w == 0) {
      const int thrA = IS2 ? 16 * (c + 1) : 16 * c - 48;  // scan1 flags
      const int thrB = 16 * c - 48;                        // scan2 flags (reuse)
      while (1) {
        bool ok = true;
        if (lane < 32) {
          u32x4 fv;
          const u32x4* fp = (const u32x4*)flags + lane;
          asm volatile("global_load_dwordx4 %0, %1, off sc0 sc1"
                       : "=v"(fv) : "v"(fp) : "memory");
          asm volatile("s_waitcnt vmcnt(0)" ::: "memory");
          ok = (int)fv[0] >= thrA && (int)fv[1] >= thrA &&
               (int)fv[2] >= thrA && (int)fv[3] >= thrA;
        } else if (IS2) {
          u32x4 fv;
          const u32x4* fp = (const u32x4*)(flags + 128) + (lane - 32);
          asm volatile("global_load_dwordx4 %0, %1, off sc0 sc1"
                       : "=v"(fv) : "v"(fp) : "memory");
          asm volatile("s_waitcnt vmcnt(0)" ::: "memory");
          ok = (int)fv[0] >= thrB && (int)fv[1] >= thrB &&
               (int)fv[2] >= thrB && (int)fv[3] >= thrB;
        }
        if (__all(ok)) break;
        __builtin_amdgcn_s_sleep(8);
      }
      if (IS2)  // invalidate L1/L2 so cached out1t reads see this chunk's data
        __builtin_amdgcn_fence(__ATOMIC_ACQUIRE, "agent");
    }
    __syncthreads();

    f32x4 acc[4][4];
#pragma unroll
    for (int i = 0; i < 4; ++i)
#pragma unroll
      for (int j = 0; j < 4; ++j) acc[i][j] = (f32x4){0.f, 0.f, 0.f, 0.f};

    for (int kt = 0; kt < 16; ++kt) {
      u32x4 aw[2][2], bv[2][2];
#pragma unroll
      for (int rr = 0; rr < 2; ++rr) {
        int row = rr * 64 + srow;
        const u32x4* bp = (const u32x4*)(Bt + (size_t)(ng * 128 + row) * 1024 + kt * 64 + qd * 16);
        bv[rr][0] = bp[0]; bv[rr][1] = bp[1];
        int rg = 512 * c + mg * 128 + row;
        if (IS2) {
          const u32x4* ap = (const u32x4*)(Abf + (size_t)rg * 1024 + kt * 64 + qd * 16);
          aw[rr][0] = ap[0]; aw[rr][1] = ap[1];   // plain cached loads
        } else {
          const f32x4* ap = (const f32x4*)(Af32 +
              ((size_t)(rg & 31) * 256 + (rg >> 5)) * 1024 + kt * 64 + qd * 16);
          f32x4 a0 = ap[0], a1 = ap[1], a2 = ap[2], a3 = ap[3];
          aw[rr][0][0] = pk2(a0[0], a0[1]); aw[rr][0][1] = pk2(a0[2], a0[3]);
          aw[rr][0][2] = pk2(a1[0], a1[1]); aw[rr][0][3] = pk2(a1[2], a1[3]);
          aw[rr][1][0] = pk2(a2[0], a2[1]); aw[rr][1][1] = pk2(a2[2], a2[3]);
          aw[rr][1][2] = pk2(a3[0], a3[1]); aw[rr][1][3] = pk2(a3[2], a3[3]);
        }
      }
      __syncthreads();  // previous MFMA reads done before overwrite
#pragma unroll
      for (int rr = 0; rr < 2; ++rr) {
        int row = rr * 64 + srow;
        u32 sw = (u32)((row & 7) << 4);
        int base = row * 128 + qd * 32;
        *(u32x4*)((char*)As + ((base) ^ sw)) = aw[rr][0];
        *(u32x4*)((char*)As + ((base + 16) ^ sw)) = aw[rr][1];
        *(u32x4*)((char*)Bs + ((base) ^ sw)) = bv[rr][0];
        *(u32x4*)((char*)Bs + ((base + 16) ^ sw)) = bv[rr][1];
      }
      __syncthreads();
#pragma unroll
      for (int k2 = 0; k2 < 2; ++k2) {
        short8 af[4], bf[4];
#pragma unroll
        for (int f = 0; f < 4; ++f) {
          af[f] = *(const short8*)((const char*)As +
                   (((wm * 64 + f * 16 + l15) * 128 + k2 * 64 + lq * 16) ^ rsw));
          bf[f] = *(const short8*)((const char*)Bs +
                   (((wn * 64 + f * 16 + l15) * 128 + k2 * 64 + lq * 16) ^ rsw));
        }
#pragma unroll
        for (int fi = 0; fi < 4; ++fi)
#pragma unroll
          for (int fj = 0; fj < 4; ++fj)
            acc[fi][fj] = MFMA16(af[fi], bf[fj], acc[fi][fj]);
      }
    }
    // ---- epilogue: +bias, store bf16 to ring slot c&3 (uncached) ----
#pragma unroll
    for (int fj = 0; fj < 4; ++fj) {
      int gc = ng * 128 + wn * 64 + fj * 16 + l15;
      float bvv = bias[permcol(gc)];
#pragma unroll
      for (int fi = 0; fi < 4; ++fi) {
        int rr0 = (c & 3) * 512 + mg * 128 + wm * 64 + fi * 16 + lq * 4;
#pragma unroll
        for (int r = 0; r < 4; ++r) {
          u32 vv = (u32)f2bf(acc[fi][fj][r] + bvv);
          const u16* cp = Cring + (size_t)(rr0 + r) * 4096 + gc;
          asm volatile("global_store_short %0, %1, off sc0 sc1"
                       :: "v"(cp), "v"(vv) : "memory");
        }
      }
    }
    asm volatile("s_waitcnt vmcnt(0)" ::: "memory");  // stores visible before count
    __syncthreads();
    if (tid == 0)
      __hip_atomic_fetch_add(gdone + c, 1, __ATOMIC_RELAXED, __HIP_MEMORY_SCOPE_AGENT);
  }
}

// -------- scan group (persistent): 128 blocks, 8 units each, K=1024 --------
// L=0: xp from xp1ring, publishes hpub + out1t (bf16 t-major), flag1.
// L=1: xp from xp2ring, publishes hpub, flag2, writes rnnout + finals.
// hpub = 64-DEEP ring (slot t&63, 4MB): each address written once per 64-step epoch
// (sc0/sc1 write-through -> L3 fresh), so h AND xp reads are PLAIN CACHED (co-XCD
// blocks hit L2); one acquire fence per epoch (t%64==0, incl. t=0 for replay safety)
// invalidates L1/L2 before any slot address is reused. Flags/publishes stay uncached.
template <int L>
__device__ void scan_grp(char* smem, int blk2,
    const u16* __restrict__ xpring, const u16* __restrict__ Wt,
    const int* __restrict__ lengths, u64* hpub, u16* out1t,
    int* flags, const int* gdone,
    float* __restrict__ outp, float* __restrict__ csf, float* __restrict__ hsf) {
  f32x4* partv = (f32x4*)smem;                   // 16KB
  u16* h_stage = (u16*)(smem + 16384);           // 512B
  float* out_stage = (float*)(smem + 17408);     // 1KB (L=1)
  const int tid = threadIdx.x;
  const int lane = tid & 63, w = tid >> 6;
  const int l15 = lane & 15, q = lane >> 4;
  const int b = (w & 1) * 16 + l15;
  const int u_local = (w >> 1) * 4 + q;
  const int len = lengths[b];
  int* flags_self = flags + L * 128;

  short8 afr[2][8];
#pragma unroll
  for (int tt = 0; tt < 2; ++tt)
#pragma unroll
    for (int ks = 0; ks < 8; ++ks)
      afr[tt][ks] = *(const short8*)(Wt + (size_t)(blk2 * 32 + tt * 16 + l15) * 1024 +
                                     w * 256 + ks * 32 + q * 8);

  f32x4 acc[2][2];
#pragma unroll
  for (int tt = 0; tt < 2; ++tt)
#pragma unroll
    for (int bc = 0; bc < 2; ++bc) acc[tt][bc] = (f32x4){0.f, 0.f, 0.f, 0.f};
  float c = 0.f, h = 0.f;

  for (int t = 0; t < 256; ++t) {
    // ---- gate: peers >= t, and xp chunk ready ----
    if (w == 0) {
      const int cidx = t >> 4;
      while (1) {
        bool ok = true;
        if (lane < 32) {
          u32x4 fv;
          const u32x4* fp = (const u32x4*)flags_self + lane;
          asm volatile("global_load_dwordx4 %0, %1, off sc0 sc1"
                       : "=v"(fv) : "v"(fp) : "memory");
          asm volatile("s_waitcnt vmcnt(0)" ::: "memory");
          ok = (int)fv[0] >= t && (int)fv[1] >= t && (int)fv[2] >= t && (int)fv[3] >= t;
        } else if (lane == 32) {
          u32 cd;
          const int* gp = gdone + cidx;
          asm volatile("global_load_dword %0, %1, off sc0 sc1"
                       : "=v"(cd) : "v"(gp) : "memory");
          asm volatile("s_waitcnt vmcnt(0)" ::: "memory");
          ok = (int)cd >= 128;
        }
        if (__all(ok)) break;
        __builtin_amdgcn_s_sleep(1);
      }
      if ((t & 63) == 0)  // epoch fence: invalidate L1/L2 before slot reuse
        __builtin_amdgcn_fence(__ATOMIC_ACQUIRE, "agent");
    }
    __syncthreads();  // BP

    // ---- xp load (CACHED; ring slot (t>>4)&3, row (t&15)*32+b) ----
    const u16* xa = xpring + ((size_t)((t >> 4) & 3) * 512 + (t & 15) * 32 + b) * 4096 +
                    blk2 * 32 + u_local * 4;
    u32x2 xpv = *(const u32x2*)xa;

    // ---- h fragments (CACHED) + MFMA ----
    if (t > 0) {
      const char* hp = (const char*)hpub + (size_t)((t - 1) & 63) * 65536;
      short8 bfv[16];
#pragma unroll
      for (int i = 0; i < 16; ++i) {
        const int ks = i >> 1, bc = i & 1;
        bfv[i] = *(const short8*)(hp + (((w * 32 + ks * 4 + q) * 32 + bc * 16 + l15) << 4));
      }
#pragma unroll
      for (int i = 0; i < 16; ++i) {
        const int ks = i >> 1, bc = i & 1;
        acc[0][bc] = MFMA16(afr[0][ks], bfv[i], acc[0][bc]);
        acc[1][bc] = MFMA16(afr[1][ks], bfv[i], acc[1][bc]);
      }
    }

    // ---- cross-wave K reduction ----
#pragma unroll
    for (int tt = 0; tt < 2; ++tt)
#pragma unroll
      for (int bc = 0; bc < 2; ++bc) {
        partv[(w * 4 + tt * 2 + bc) * 64 + lane] = acc[tt][bc];
        acc[tt][bc] = (f32x4){0.f, 0.f, 0.f, 0.f};
      }
    __syncthreads();  // B1
    f32x4 s = (f32x4){0.f, 0.f, 0.f, 0.f};
#pragma unroll
    for (int w2 = 0; w2 < 4; ++w2) s += partv[(w2 * 4 + w) * 64 + lane];

    float zi = s[0] + bf2f((u16)(xpv[0] & 0xffffu));
    float zj = s[1] + bf2f((u16)(xpv[0] >> 16));
    float zf = s[2] + bf2f((u16)(xpv[1] & 0xffffu)) + 1.f;  // FORGET_BIAS
    float zo = s[3] + bf2f((u16)(xpv[1] >> 16));
    float cn = sigm(zf) * c + sigm(zi) * tanh_(zj);
    float hn = sigm(zo) * tanh_(cn);
    bool mk = t < len;
    c = mk ? cn : c;
    h = mk ? hn : h;
    float ov = mk ? hn : 0.f;
    h_stage[b * 8 + u_local] = f2bf(ov);
    if (L) out_stage[b * 8 + u_local] = ov;
    __syncthreads();  // B2

    // ---- publish (uncached write-through), drain, flag ----
    if (tid < 32) {
      u64* hd = hpub + (size_t)(t & 63) * 8192;
      const u64* hsrc = (const u64*)h_stage;
      u64 v0 = hsrc[tid * 2], v1 = hsrc[tid * 2 + 1];
      __hip_atomic_store(hd + (blk2 * 32 + tid) * 2, v0, __ATOMIC_RELAXED,
                         __HIP_MEMORY_SCOPE_AGENT);
      __hip_atomic_store(hd + (blk2 * 32 + tid) * 2 + 1, v1, __ATOMIC_RELAXED,
                         __HIP_MEMORY_SCOPE_AGENT);
      if (!L) {  // out1 for GEMM2, t-major rows
        u64* od = (u64*)(out1t + ((size_t)t * 32 + tid) * 1024 + blk2 * 8);
        __hip_atomic_store(od, v0, __ATOMIC_RELAXED, __HIP_MEMORY_SCOPE_AGENT);
        __hip_atomic_store(od + 1, v1, __ATOMIC_RELAXED, __HIP_MEMORY_SCOPE_AGENT);
      }
    }
    asm volatile("s_waitcnt vmcnt(0)" ::: "memory");  // visible before flag
    if (tid == 0)
      __hip_atomic_store(flags_self + blk2, t + 1, __ATOMIC_RELAXED,
                         __HIP_MEMORY_SCOPE_AGENT);
    if (L && tid < 32) {  // rnnout rows (b=tid, t)
      const f32x4* osrc = (const f32x4*)out_stage;
      f32x4 o0 = osrc[tid * 2], o1 = osrc[tid * 2 + 1];
      f32x4* od = (f32x4*)(outp + ((size_t)tid * 256 + t) * 1024 + blk2 * 8);
      od[0] = o0; od[1] = o1;
    }
  }
  csf[L * 32768 + b * 1024 + blk2 * 8 + u_local] = c;
  hsf[L * 32768 + b * 1024 + blk2 * 8 + u_local] = h;
}

// -------- 4-group persistent pipeline: G1 | scan1 | G2 | scan2, 128 blocks each --------
__global__ __launch_bounds__(256, 2) void lstm_pipe(
    const float* __restrict__ x, const int* __restrict__ lengths,
    const float* __restrict__ bias,
    const u16* __restrict__ WxT1, const u16* __restrict__ WxT2,
    const u16* __restrict__ WhT1, const u16* __restrict__ WhT2,
    u16* xp1ring, u16* xp2ring, u16* out1t,
    u64* hpub1, u64* hpub2, int* flags, float* outp) {
  __shared__ __align__(16) char smem[32768];
  int* g1done = flags + 256;
  int* g2done = flags + 272;
  const int g = blockIdx.x >> 7, gb = blockIdx.x & 127;
  float* csf = outp + RN_;
  float* hsf = csf + 65536;
  if (g == 0)
    gemm_grp<0>(smem, gb, x, nullptr, WxT1, bias, xp1ring, flags, g1done);
  else if (g == 1)
    scan_grp<0>(smem, gb, xp1ring, WhT1, lengths, hpub1, out1t, flags, g1done,
                outp, csf, hsf);
  else if (g == 2)
    gemm_grp<1>(smem, gb, nullptr, out1t, WxT2, bias + 4096, xp2ring, flags, g2done);
  else
    scan_grp<1>(smem, gb, xp2ring, WhT2, lengths, hpub2, nullptr, flags, g2done,
                outp, csf, hsf);
}

// -------- workspace layout (fits proven 96.5MB budget; total 88MB+) --------
#define WS_WXT1 0u
#define WS_WXT2 (8u << 20)
#define WS_WHT1 (16u << 20)
#define WS_WHT2 (24u << 20)
#define WS_XP1 (32u << 20)    // 4 slots x 512 rows x 4096 x 2B = 16MB
#define WS_XP2 (48u << 20)    // 16MB
#define WS_OUT1 (64u << 20)   // 8192 x 1024 x 2B = 16MB
#define WS_HPUB1 (80u << 20)  // 64 slots x 64KB = 4MB
#define WS_HPUB2 (84u << 20)  // 4MB
#define WS_FLAGS (88u << 20)  // 256 flags + 16 + 16 counters

extern "C" void kernel_launch(void* const* d_in, const int* in_sizes, int n_in,
                              void* d_out, int out_size, void* d_ws, size_t ws_size,
                              hipStream_t stream) {
  const float* x = (const float*)d_in[0];
  const int* lengths = (const int*)d_in[1];
  const float* Wx = (const float*)d_in[2];
  const float* Wh = (const float*)d_in[3];
  const float* bias = (const float*)d_in[4];
  float* outp = (float*)d_out;

  if (ws_size < (size_t)WS_FLAGS + 4096) return;  // fail loudly (output stays poison)

  char* ws = (char*)d_ws;
  u16* WxT1 = (u16*)(ws + WS_WXT1);
  u16* WxT2 = (u16*)(ws + WS_WXT2);
  u16* WhT1 = (u16*)(ws + WS_WHT1);
  u16* WhT2 = (u16*)(ws + WS_WHT2);
  u16* xp1ring = (u16*)(ws + WS_XP1);
  u16* xp2ring = (u16*)(ws + WS_XP2);
  u16* out1t = (u16*)(ws + WS_OUT1);
  u64* hpub1 = (u64*)(ws + WS_HPUB1);
  u64* hpub2 = (u64*)(ws + WS_HPUB2);
  int* flags = (int*)(ws + WS_FLAGS);

  hipMemsetAsync(flags, 0, 2048, stream);
  transpose_convert<<<4096, 256, 0, stream>>>(Wx, Wh, WxT1, WxT2, WhT1, WhT2);
  lstm_pipe<<<512, 256, 0, stream>>>(x, lengths, bias, WxT1, WxT2, WhT1, WhT2,
                                     xp1ring, xp2ring, out1t, hpub1, hpub2, flags, outp);
}

// Round 7
// 1741.992 us; speedup vs baseline: 1.1452x; 1.1452x over previous
//
#include <hip/hip_runtime.h>

typedef unsigned short u16;
typedef unsigned int u32;
typedef unsigned long long u64;
typedef __attribute__((ext_vector_type(8))) short short8;
typedef __attribute__((ext_vector_type(4))) float f32x4;
typedef __attribute__((ext_vector_type(4))) u32 u32x4;
typedef __attribute__((ext_vector_type(2))) u32 u32x2;

#define RN_ 8388608  // B*T*H
#define MFMA16(a, b, c) __builtin_amdgcn_mfma_f32_16x16x32_bf16(a, b, c, 0, 0, 0)

__device__ __forceinline__ u16 f2bf(float f) {
  union { float f; u32 u; } v; v.f = f;
  u32 r = v.u + 0x7fffu + ((v.u >> 16) & 1u);  // RNE (inputs finite)
  return (u16)(r >> 16);
}
__device__ __forceinline__ float bf2f(u16 h) {
  union { u32 u; float f; } v; v.u = ((u32)h) << 16;
  return v.f;
}
__device__ __forceinline__ u32 pk2(float a, float b) {
  return (u32)f2bf(a) | ((u32)f2bf(b) << 16);
}
// scan column ordering (absolute R in [0,4096)):
// R = (k>>3 block of 8 units)*32 + (u&7)*4 + gate  ->  original g = gate*1024 + unit
__device__ __forceinline__ int permcol(int R) {
  return (R & 3) * 1024 + ((R >> 5) << 3) + ((R >> 2) & 7);
}
__device__ __forceinline__ float sigm(float x) { return 1.f / (1.f + __expf(-x)); }
__device__ __forceinline__ float tanh_(float x) {
  float e = __expf(2.f * x);
  return 1.f - 2.f / (e + 1.f);
}

// -------- transpose + convert + permute: four [4096][1024] bf16 buffers --------
__global__ __launch_bounds__(256) void transpose_convert(
    const float* __restrict__ Wx, const float* __restrict__ Wh,
    u16* __restrict__ WxT1, u16* __restrict__ WxT2,
    u16* __restrict__ WhT1, u16* __restrict__ WhT2) {
  __shared__ float lds[64][65];
  const int bid = blockIdx.x, tid = threadIdx.x;
  const int sel = bid >> 10;
  const int tile = bid & 1023;
  const int kt = tile & 15, rt = tile >> 4;  // 16 k-tiles x 64 R-tiles
  const float* src;
  u16* dst;
  if (sel == 0)      { src = Wx;                       dst = WxT1; }
  else if (sel == 1) { src = Wx + (size_t)1024 * 4096; dst = WxT2; }
  else if (sel == 2) { src = Wh;                       dst = WhT1; }
  else               { src = Wh + (size_t)1024 * 4096; dst = WhT2; }
#pragma unroll
  for (int ii = 0; ii < 16; ++ii) {
    int idx = ii * 256 + tid;
    int r = idx >> 6, c = idx & 63;
    int run = c >> 3, u = c & 7;
    int blkLoc = run >> 2, gate = run & 3;
    int g = gate * 1024 + (rt * 2 + blkLoc) * 8 + u;
    lds[r][blkLoc * 32 + u * 4 + gate] = src[(size_t)(kt * 64 + r) * 4096 + g];
  }
  __syncthreads();
#pragma unroll
  for (int ii = 0; ii < 16; ++ii) {
    int idx = ii * 256 + tid;
    int rw = idx >> 6, cw = idx & 63;
    dst[(size_t)(rt * 64 + rw) * 1024 + kt * 64 + cw] = f2bf(lds[cw][rw]);
  }
}

// -------- chunked GEMM group (persistent): 128 blocks, 16 chunks of 512 rows --------
// IS2=0: A = x (f32, rows remapped b*256+t), out -> xp1ring; gate: xp1 ring reuse.
// IS2=1: A = h1 read DIRECTLY from full-depth hpub1 ring (uncached); gate: scan1
//        chunk published + xp2 ring reuse vs scan2.
// C rows t-major (r = t*32+b), cols permuted; bias added here. C stores uncached.
// flags layout: [0..63] scan1, [64..127] scan2.
template <int IS2>
__device__ void gemm_grp(char* smem, int gb,
    const float* __restrict__ Af32, const u16* __restrict__ Ahp,
    const u16* __restrict__ Bt, const float* __restrict__ bias,
    u16* __restrict__ Cring, const int* flags, int* gdone) {
  u16* As = (u16*)smem;
  u16* Bs = (u16*)(smem + 16384);
  const int tid = threadIdx.x;
  const int lane = tid & 63, w = tid >> 6;
  const int wm = w >> 1, wn = w & 1;
  const int l15 = lane & 15, lq = lane >> 4;
  const int srow = tid >> 2, qd = tid & 3;
  const int mg = gb >> 5, ng = gb & 31;
  const u32 rsw = (u32)((l15 & 7) << 4);

  for (int c = 0; c < 16; ++c) {
    // ---- gate ----
    if (w == 0) {
      const int thrA = IS2 ? 16 * (c + 1) : 16 * c - 48;  // scan1 flags
      const int thrB = 16 * c - 48;                        // scan2 flags (xp2 reuse)
      while (1) {
        bool ok = true;
        if (lane < 16) {
          u32x4 fv;
          const u32x4* fp = (const u32x4*)flags + lane;
          asm volatile("global_load_dwordx4 %0, %1, off sc0 sc1"
                       : "=v"(fv) : "v"(fp) : "memory");
          asm volatile("s_waitcnt vmcnt(0)" ::: "memory");
          ok = (int)fv[0] >= thrA && (int)fv[1] >= thrA &&
               (int)fv[2] >= thrA && (int)fv[3] >= thrA;
        } else if (IS2 && lane < 32) {
          u32x4 fv;
          const u32x4* fp = (const u32x4*)(flags + 64) + (lane - 16);
          asm volatile("global_load_dwordx4 %0, %1, off sc0 sc1"
                       : "=v"(fv) : "v"(fp) : "memory");
          asm volatile("s_waitcnt vmcnt(0)" ::: "memory");
          ok = (int)fv[0] >= thrB && (int)fv[1] >= thrB &&
               (int)fv[2] >= thrB && (int)fv[3] >= thrB;
        }
        if (__all(ok)) break;
        __builtin_amdgcn_s_sleep(8);
      }
    }
    __syncthreads();

    f32x4 acc[4][4];
#pragma unroll
    for (int i = 0; i < 4; ++i)
#pragma unroll
      for (int j = 0; j < 4; ++j) acc[i][j] = (f32x4){0.f, 0.f, 0.f, 0.f};

    for (int kt = 0; kt < 16; ++kt) {
      u32x4 aw[2][2], bv[2][2];
#pragma unroll
      for (int rr = 0; rr < 2; ++rr) {
        int row = rr * 64 + srow;
        const u32x4* bp = (const u32x4*)(Bt + (size_t)(ng * 128 + row) * 1024 + kt * 64 + qd * 16);
        bv[rr][0] = bp[0]; bv[rr][1] = bp[1];
        int rg = 512 * c + mg * 128 + row;
        if (IS2) {
          // h1 from hpub1 ring: slot t=rg>>5, batch b=rg&31, k-pack p=kt*8+qd*2
          int tq = rg >> 5, b2 = rg & 31;
          int p = kt * 8 + qd * 2;
          const char* ap = (const char*)Ahp + (size_t)tq * 65536 +
                           (size_t)(p * 32 + b2) * 16;
          asm volatile("global_load_dwordx4 %0, %1, off sc0 sc1"
                       : "=v"(aw[rr][0]) : "v"(ap) : "memory");
          asm volatile("global_load_dwordx4 %0, %1, off sc0 sc1"
                       : "=v"(aw[rr][1]) : "v"(ap + 512) : "memory");
        } else {
          const f32x4* ap = (const f32x4*)(Af32 +
              ((size_t)(rg & 31) * 256 + (rg >> 5)) * 1024 + kt * 64 + qd * 16);
          f32x4 a0 = ap[0], a1 = ap[1], a2 = ap[2], a3 = ap[3];
          aw[rr][0][0] = pk2(a0[0], a0[1]); aw[rr][0][1] = pk2(a0[2], a0[3]);
          aw[rr][0][2] = pk2(a1[0], a1[1]); aw[rr][0][3] = pk2(a1[2], a1[3]);
          aw[rr][1][0] = pk2(a2[0], a2[1]); aw[rr][1][1] = pk2(a2[2], a2[3]);
          aw[rr][1][2] = pk2(a3[0], a3[1]); aw[rr][1][3] = pk2(a3[2], a3[3]);
        }
      }
      __syncthreads();  // previous MFMA reads done before overwrite
      if (IS2) {
        asm volatile("s_waitcnt vmcnt(0)" ::: "memory");  // asm loads landed
        __builtin_amdgcn_sched_barrier(0);
      }
#pragma unroll
      for (int rr = 0; rr < 2; ++rr) {
        int row = rr * 64 + srow;
        u32 sw = (u32)((row & 7) << 4);
        int base = row * 128 + qd * 32;
        *(u32x4*)((char*)As + ((base) ^ sw)) = aw[rr][0];
        *(u32x4*)((char*)As + ((base + 16) ^ sw)) = aw[rr][1];
        *(u32x4*)((char*)Bs + ((base) ^ sw)) = bv[rr][0];
        *(u32x4*)((char*)Bs + ((base + 16) ^ sw)) = bv[rr][1];
      }
      __syncthreads();
#pragma unroll
      for (int k2 = 0; k2 < 2; ++k2) {
        short8 af[4], bf[4];
#pragma unroll
        for (int f = 0; f < 4; ++f) {
          af[f] = *(const short8*)((const char*)As +
                   (((wm * 64 + f * 16 + l15) * 128 + k2 * 64 + lq * 16) ^ rsw));
          bf[f] = *(const short8*)((const char*)Bs +
                   (((wn * 64 + f * 16 + l15) * 128 + k2 * 64 + lq * 16) ^ rsw));
        }
#pragma unroll
        for (int fi = 0; fi < 4; ++fi)
#pragma unroll
          for (int fj = 0; fj < 4; ++fj)
            acc[fi][fj] = MFMA16(af[fi], bf[fj], acc[fi][fj]);
      }
    }
    // ---- epilogue: +bias, store bf16 to ring slot c&3 (uncached) ----
#pragma unroll
    for (int fj = 0; fj < 4; ++fj) {
      int gc = ng * 128 + wn * 64 + fj * 16 + l15;
      float bvv = bias[permcol(gc)];
#pragma unroll
      for (int fi = 0; fi < 4; ++fi) {
        int rr0 = (c & 3) * 512 + mg * 128 + wm * 64 + fi * 16 + lq * 4;
#pragma unroll
        for (int r = 0; r < 4; ++r) {
          u32 vv = (u32)f2bf(acc[fi][fj][r] + bvv);
          const u16* cp = Cring + (size_t)(rr0 + r) * 4096 + gc;
          asm volatile("global_store_short %0, %1, off sc0 sc1"
                       :: "v"(cp), "v"(vv) : "memory");
        }
      }
    }
    asm volatile("s_waitcnt vmcnt(0)" ::: "memory");  // stores visible before count
    __syncthreads();
    if (tid == 0)
      __hip_atomic_fetch_add(gdone + c, 1, __ATOMIC_RELAXED, __HIP_MEMORY_SCOPE_AGENT);
  }
}

// -------- scan group (persistent): 64 blocks, 16 units each, K=1024 --------
// Halved block count halves the uncached h-broadcast read volume (4MB/step/scan).
// hpub = FULL-DEPTH ring (256 slots x 64KB = 16MB): no slot reuse within a
// dispatch -> no fences, no reuse gate terms; all data reads uncached (sc0 sc1),
// so graph replays are safe too. Publish layout [k>>3][b] x 16B.
template <int L>
__device__ void scan_grp(char* smem, int nb,
    const u16* __restrict__ xpring, const u16* __restrict__ Wt,
    const int* __restrict__ lengths, u64* hpub,
    int* flags_self, const int* gdone,
    float* __restrict__ outp, float* __restrict__ csf, float* __restrict__ hsf) {
  f32x4* partv = (f32x4*)smem;                   // 32KB
  u16* h_stage = (u16*)(smem + 32768);           // 1KB  [b][16u]
  float* out_stage = (float*)(smem + 33792);     // 2KB  [b][16u] (L=1)
  const int tid = threadIdx.x;
  const int lane = tid & 63, w = tid >> 6;
  const int l15 = lane & 15, q = lane >> 4;
  const int b = (w & 1) * 16 + l15;
  const int u0 = (w >> 1) * 4 + q;  // 0..7; second unit = u0+8
  const int len = lengths[b];

  // Wh A-fragments register-resident: 32 x short8 = 128 VGPR
  short8 afr[4][8];
#pragma unroll
  for (int tt = 0; tt < 4; ++tt)
#pragma unroll
    for (int ks = 0; ks < 8; ++ks)
      afr[tt][ks] = *(const short8*)(Wt + (size_t)(nb * 64 + tt * 16 + l15) * 1024 +
                                     w * 256 + ks * 32 + q * 8);

  f32x4 acc[4][2];
#pragma unroll
  for (int tt = 0; tt < 4; ++tt)
#pragma unroll
    for (int bc = 0; bc < 2; ++bc) acc[tt][bc] = (f32x4){0.f, 0.f, 0.f, 0.f};
  float c0 = 0.f, h0 = 0.f, c1 = 0.f, h1 = 0.f;

  for (int t = 0; t < 256; ++t) {
    // ---- gate: peers >= t, xp chunk ready ----
    if (w == 0) {
      const int cidx = t >> 4;
      while (1) {
        bool ok = true;
        if (lane < 16) {
          u32x4 fv;
          const u32x4* fp = (const u32x4*)flags_self + lane;
          asm volatile("global_load_dwordx4 %0, %1, off sc0 sc1"
                       : "=v"(fv) : "v"(fp) : "memory");
          asm volatile("s_waitcnt vmcnt(0)" ::: "memory");
          ok = (int)fv[0] >= t && (int)fv[1] >= t && (int)fv[2] >= t && (int)fv[3] >= t;
        } else if (lane == 16) {
          u32 cd;
          const int* gp = gdone + cidx;
          asm volatile("global_load_dword %0, %1, off sc0 sc1"
                       : "=v"(cd) : "v"(gp) : "memory");
          asm volatile("s_waitcnt vmcnt(0)" ::: "memory");
          ok = (int)cd >= 128;
        }
        if (__all(ok)) break;
        __builtin_amdgcn_s_sleep(1);
      }
    }
    __syncthreads();  // BP

    // ---- xp loads (uncached; ring slot (t>>4)&3, row (t&15)*32+b), 2 units ----
    const u16* xa = xpring + ((size_t)((t >> 4) & 3) * 512 + (t & 15) * 32 + b) * 4096 +
                    nb * 64 + u0 * 4;
    u32x2 xpv0, xpv1;
    asm volatile("global_load_dwordx2 %0, %1, off sc0 sc1"
                 : "=v"(xpv0) : "v"(xa) : "memory");
    asm volatile("global_load_dwordx2 %0, %1, off sc0 sc1"
                 : "=v"(xpv1) : "v"(xa + 32) : "memory");

    // ---- h fragments (uncached, 2 groups of 8) + 64 MFMA/wave ----
    if (t > 0) {
      const char* hp = (const char*)hpub + (size_t)(t - 1) * 65536;
#pragma unroll
      for (int g2 = 0; g2 < 2; ++g2) {
        short8 bfv[8];
#pragma unroll
        for (int i = 0; i < 8; ++i) {
          const int ks = g2 * 4 + (i >> 1), bc = i & 1;
          const char* p = hp + (((w * 32 + ks * 4 + q) * 32 + bc * 16 + l15) << 4);
          asm volatile("global_load_dwordx4 %0, %1, off sc0 sc1"
                       : "=v"(bfv[i]) : "v"(p) : "memory");
        }
        asm volatile("s_waitcnt vmcnt(0)" ::: "memory");
        __builtin_amdgcn_sched_barrier(0);
#pragma unroll
        for (int i = 0; i < 8; ++i) {
          const int ks = g2 * 4 + (i >> 1), bc = i & 1;
          acc[0][bc] = MFMA16(afr[0][ks], bfv[i], acc[0][bc]);
          acc[1][bc] = MFMA16(afr[1][ks], bfv[i], acc[1][bc]);
          acc[2][bc] = MFMA16(afr[2][ks], bfv[i], acc[2][bc]);
          acc[3][bc] = MFMA16(afr[3][ks], bfv[i], acc[3][bc]);
        }
      }
    } else {
      asm volatile("s_waitcnt vmcnt(0)" ::: "memory");
      __builtin_amdgcn_sched_barrier(0);
    }

    // ---- cross-wave K reduction (8 combos, 32 slots) ----
#pragma unroll
    for (int tt = 0; tt < 4; ++tt)
#pragma unroll
      for (int bc = 0; bc < 2; ++bc) {
        partv[(w * 8 + tt * 2 + bc) * 64 + lane] = acc[tt][bc];
        acc[tt][bc] = (f32x4){0.f, 0.f, 0.f, 0.f};
      }
    __syncthreads();  // B1
    f32x4 s0 = (f32x4){0.f, 0.f, 0.f, 0.f};
    f32x4 s1 = (f32x4){0.f, 0.f, 0.f, 0.f};
#pragma unroll
    for (int w2 = 0; w2 < 4; ++w2) {
      s0 += partv[(w2 * 8 + w) * 64 + lane];       // combo w   -> unit u0
      s1 += partv[(w2 * 8 + 4 + w) * 64 + lane];   // combo w+4 -> unit u0+8
    }

    bool mk = t < len;
    {
      float zi = s0[0] + bf2f((u16)(xpv0[0] & 0xffffu));
      float zj = s0[1] + bf2f((u16)(xpv0[0] >> 16));
      float zf = s0[2] + bf2f((u16)(xpv0[1] & 0xffffu)) + 1.f;  // FORGET_BIAS
      float zo = s0[3] + bf2f((u16)(xpv0[1] >> 16));
      float cn = sigm(zf) * c0 + sigm(zi) * tanh_(zj);
      float hn = sigm(zo) * tanh_(cn);
      c0 = mk ? cn : c0;
      h0 = mk ? hn : h0;
      float ov = mk ? hn : 0.f;
      h_stage[b * 16 + u0] = f2bf(ov);
      if (L) out_stage[b * 16 + u0] = ov;
    }
    {
      float zi = s1[0] + bf2f((u16)(xpv1[0] & 0xffffu));
      float zj = s1[1] + bf2f((u16)(xpv1[0] >> 16));
      float zf = s1[2] + bf2f((u16)(xpv1[1] & 0xffffu)) + 1.f;
      float zo = s1[3] + bf2f((u16)(xpv1[1] >> 16));
      float cn = sigm(zf) * c1 + sigm(zi) * tanh_(zj);
      float hn = sigm(zo) * tanh_(cn);
      c1 = mk ? cn : c1;
      h1 = mk ? hn : h1;
      float ov = mk ? hn : 0.f;
      h_stage[b * 16 + u0 + 8] = f2bf(ov);
      if (L) out_stage[b * 16 + u0 + 8] = ov;
    }
    __syncthreads();  // B2

    // ---- publish (uncached), drain, flag ----
    if (tid < 64) {  // 2 k-packs x 32 batches x 16B
      int p = tid >> 5, bb = tid & 31;
      const u64* hsrc = (const u64*)h_stage;
      u64 v0 = hsrc[bb * 4 + p * 2], v1 = hsrc[bb * 4 + p * 2 + 1];
      u64* hd = hpub + (size_t)t * 8192 + ((size_t)((nb * 2 + p) * 32 + bb)) * 2;
      __hip_atomic_store(hd, v0, __ATOMIC_RELAXED, __HIP_MEMORY_SCOPE_AGENT);
      __hip_atomic_store(hd + 1, v1, __ATOMIC_RELAXED, __HIP_MEMORY_SCOPE_AGENT);
    }
    asm volatile("s_waitcnt vmcnt(0)" ::: "memory");  // visible before flag
    if (tid == 0)
      __hip_atomic_store(flags_self + nb, t + 1, __ATOMIC_RELAXED,
                         __HIP_MEMORY_SCOPE_AGENT);
    if (L && tid < 128) {  // rnnout rows (b, t), 16 cols
      int bb = tid >> 2, part = tid & 3;
      f32x4 ov = *(const f32x4*)(out_stage + bb * 16 + part * 4);
      *(f32x4*)(outp + ((size_t)bb * 256 + t) * 1024 + nb * 16 + part * 4) = ov;
    }
  }
  csf[L * 32768 + b * 1024 + nb * 16 + u0] = c0;
  csf[L * 32768 + b * 1024 + nb * 16 + u0 + 8] = c1;
  hsf[L * 32768 + b * 1024 + nb * 16 + u0] = h0;
  hsf[L * 32768 + b * 1024 + nb * 16 + u0 + 8] = h1;
}

// -------- persistent pipeline: G1 128 | scan1 64 | G2 128 | scan2 64 --------
__global__ __launch_bounds__(256, 2) void lstm_pipe(
    const float* __restrict__ x, const int* __restrict__ lengths,
    const float* __restrict__ bias,
    const u16* __restrict__ WxT1, const u16* __restrict__ WxT2,
    const u16* __restrict__ WhT1, const u16* __restrict__ WhT2,
    u16* xp1ring, u16* xp2ring,
    u64* hpub1, u64* hpub2, int* flags, float* outp) {
  __shared__ __align__(16) char smem[35840];
  int* g1done = flags + 128;
  int* g2done = flags + 144;
  const int bid = blockIdx.x;
  float* csf = outp + RN_;
  float* hsf = csf + 65536;
  if (bid < 128)
    gemm_grp<0>(smem, bid, x, nullptr, WxT1, bias, xp1ring, flags, g1done);
  else if (bid < 192)
    scan_grp<0>(smem, bid - 128, xp1ring, WhT1, lengths, hpub1, flags, g1done,
                outp, csf, hsf);
  else if (bid < 320)
    gemm_grp<1>(smem, bid - 192, nullptr, (const u16*)hpub1, WxT2, bias + 4096,
                xp2ring, flags, g2done);
  else
    scan_grp<1>(smem, bid - 320, xp2ring, WhT2, lengths, hpub2, flags + 64, g2done,
                outp, csf, hsf);
}

// -------- workspace layout (96MB + flags; r1 proved 96.5MB OK) --------
#define WS_WXT1 0u
#define WS_WXT2 (8u << 20)
#define WS_WHT1 (16u << 20)
#define WS_WHT2 (24u << 20)
#define WS_XP1 (32u << 20)    // 4 slots x 512 rows x 4096 x 2B = 16MB
#define WS_XP2 (48u << 20)    // 16MB
#define WS_HPUB1 (64u << 20)  // 256 slots x 64KB = 16MB (full depth)
#define WS_HPUB2 (80u << 20)  // 16MB
#define WS_FLAGS (96u << 20)  // 128 scan flags + 2x16 chunk counters

extern "C" void kernel_launch(void* const* d_in, const int* in_sizes, int n_in,
                              void* d_out, int out_size, void* d_ws, size_t ws_size,
                              hipStream_t stream) {
  const float* x = (const float*)d_in[0];
  const int* lengths = (const int*)d_in[1];
  const float* Wx = (const float*)d_in[2];
  const float* Wh = (const float*)d_in[3];
  const float* bias = (const float*)d_in[4];
  float* outp = (float*)d_out;

  if (ws_size < (size_t)WS_FLAGS + 4096) return;  // fail loudly (output stays poison)

  char* ws = (char*)d_ws;
  u16* WxT1 = (u16*)(ws + WS_WXT1);
  u16* WxT2 = (u16*)(ws + WS_WXT2);
  u16* WhT1 = (u16*)(ws + WS_WHT1);
  u16* WhT2 = (u16*)(ws + WS_WHT2);
  u16* xp1ring = (u16*)(ws + WS_XP1);
  u16* xp2ring = (u16*)(ws + WS_XP2);
  u64* hpub1 = (u64*)(ws + WS_HPUB1);
  u64* hpub2 = (u64*)(ws + WS_HPUB2);
  int* flags = (int*)(ws + WS_FLAGS);

  hipMemsetAsync(flags, 0, 2048, stream);
  transpose_convert<<<4096, 256, 0, stream>>>(Wx, Wh, WxT1, WxT2, WhT1, WhT2);
  lstm_pipe<<<384, 256, 0, stream>>>(x, lengths, bias, WxT1, WxT2, WhT1, WhT2,
                                     xp1ring, xp2ring, hpub1, hpub2, flags, outp);
}

// Round 8
// 1268.663 us; speedup vs baseline: 1.5725x; 1.3731x over previous
//
#include <hip/hip_runtime.h>

typedef unsigned short u16;
typedef unsigned int u32;
typedef unsigned long long u64;
typedef __attribute__((ext_vector_type(8))) short short8;
typedef __attribute__((ext_vector_type(4))) float f32x4;
typedef __attribute__((ext_vector_type(4))) u32 u32x4;
typedef __attribute__((ext_vector_type(2))) u32 u32x2;

#define RN_ 8388608  // B*T*H
#define MFMA16(a, b, c) __builtin_amdgcn_mfma_f32_16x16x32_bf16(a, b, c, 0, 0, 0)

__device__ __forceinline__ u16 f2bf(float f) {
  union { float f; u32 u; } v; v.f = f;
  u32 r = v.u + 0x7fffu + ((v.u >> 16) & 1u);  // RNE (inputs finite)
  return (u16)(r >> 16);
}
__device__ __forceinline__ float bf2f(u16 h) {
  union { u32 u; float f; } v; v.u = ((u32)h) << 16;
  return v.f;
}
__device__ __forceinline__ u32 pk2(float a, float b) {
  return (u32)f2bf(a) | ((u32)f2bf(b) << 16);
}
// scan column ordering (absolute R in [0,4096)):
// R = (k>>3 block of 8 units)*32 + (u&7)*4 + gate  ->  original g = gate*1024 + unit
__device__ __forceinline__ int permcol(int R) {
  return (R & 3) * 1024 + ((R >> 5) << 3) + ((R >> 2) & 7);
}
__device__ __forceinline__ float sigm(float x) { return 1.f / (1.f + __expf(-x)); }
__device__ __forceinline__ float tanh_(float x) {
  float e = __expf(2.f * x);
  return 1.f - 2.f / (e + 1.f);
}

// -------- transpose + convert + permute: four [4096][1024] bf16 buffers --------
__global__ __launch_bounds__(256) void transpose_convert(
    const float* __restrict__ Wx, const float* __restrict__ Wh,
    u16* __restrict__ WxT1, u16* __restrict__ WxT2,
    u16* __restrict__ WhT1, u16* __restrict__ WhT2) {
  __shared__ float lds[64][65];
  const int bid = blockIdx.x, tid = threadIdx.x;
  const int sel = bid >> 10;
  const int tile = bid & 1023;
  const int kt = tile & 15, rt = tile >> 4;  // 16 k-tiles x 64 R-tiles
  const float* src;
  u16* dst;
  if (sel == 0)      { src = Wx;                       dst = WxT1; }
  else if (sel == 1) { src = Wx + (size_t)1024 * 4096; dst = WxT2; }
  else if (sel == 2) { src = Wh;                       dst = WhT1; }
  else               { src = Wh + (size_t)1024 * 4096; dst = WhT2; }
#pragma unroll
  for (int ii = 0; ii < 16; ++ii) {
    int idx = ii * 256 + tid;
    int r = idx >> 6, c = idx & 63;
    int run = c >> 3, u = c & 7;
    int blkLoc = run >> 2, gate = run & 3;
    int g = gate * 1024 + (rt * 2 + blkLoc) * 8 + u;
    lds[r][blkLoc * 32 + u * 4 + gate] = src[(size_t)(kt * 64 + r) * 4096 + g];
  }
  __syncthreads();
#pragma unroll
  for (int ii = 0; ii < 16; ++ii) {
    int idx = ii * 256 + tid;
    int rw = idx >> 6, cw = idx & 63;
    dst[(size_t)(rt * 64 + rw) * 1024 + kt * 64 + cw] = f2bf(lds[cw][rw]);
  }
}

// -------- chunked GEMM group (persistent): 64 blocks, 16 chunks, 2 tiles/chunk --------
// IS2=0: A = x (f32, rows remapped b*256+t), out -> xp1ring; gate: xp1 ring reuse.
// IS2=1: A = h1 read DIRECTLY from full-depth hpub1 ring (uncached); gate: scan1
//        chunk published + xp2 ring reuse vs scan2.
// C rows t-major (r = t*32+b), cols permuted; bias added here. C stores uncached.
// flags layout: [0..63] scan1, [64..127] scan2.
template <int IS2>
__device__ void gemm_grp(char* smem, int gb,
    const float* __restrict__ Af32, const u16* __restrict__ Ahp,
    const u16* __restrict__ Bt, const float* __restrict__ bias,
    u16* __restrict__ Cring, const int* flags, int* gdone) {
  u16* As = (u16*)smem;
  u16* Bs = (u16*)(smem + 16384);
  const int tid = threadIdx.x;
  const int lane = tid & 63, w = tid >> 6;
  const int wm = w >> 1, wn = w & 1;
  const int l15 = lane & 15, lq = lane >> 4;
  const int srow = tid >> 2, qd = tid & 3;
  const u32 rsw = (u32)((l15 & 7) << 4);

  for (int c = 0; c < 16; ++c) {
    // ---- gate (once per chunk) ----
    if (w == 0) {
      const int thrA = IS2 ? 16 * (c + 1) : 16 * c - 48;  // scan1 flags
      const int thrB = 16 * c - 48;                        // scan2 flags (xp2 reuse)
      while (1) {
        bool ok = true;
        if (lane < 16) {
          u32x4 fv;
          const u32x4* fp = (const u32x4*)flags + lane;
          asm volatile("global_load_dwordx4 %0, %1, off sc0 sc1"
                       : "=v"(fv) : "v"(fp) : "memory");
          asm volatile("s_waitcnt vmcnt(0)" ::: "memory");
          ok = (int)fv[0] >= thrA && (int)fv[1] >= thrA &&
               (int)fv[2] >= thrA && (int)fv[3] >= thrA;
        } else if (IS2 && lane < 32) {
          u32x4 fv;
          const u32x4* fp = (const u32x4*)(flags + 64) + (lane - 16);
          asm volatile("global_load_dwordx4 %0, %1, off sc0 sc1"
                       : "=v"(fv) : "v"(fp) : "memory");
          asm volatile("s_waitcnt vmcnt(0)" ::: "memory");
          ok = (int)fv[0] >= thrB && (int)fv[1] >= thrB &&
               (int)fv[2] >= thrB && (int)fv[3] >= thrB;
        }
        if (__all(ok)) break;
        __builtin_amdgcn_s_sleep(8);
      }
    }
    __syncthreads();

    for (int e = 0; e < 2; ++e) {  // 2 tiles per block per chunk
      const int ti = gb * 2 + e;
      const int mg = ti >> 5, ng = ti & 31;

      f32x4 acc[4][4];
#pragma unroll
      for (int i = 0; i < 4; ++i)
#pragma unroll
        for (int j = 0; j < 4; ++j) acc[i][j] = (f32x4){0.f, 0.f, 0.f, 0.f};

      for (int kt = 0; kt < 16; ++kt) {
        u32x4 aw[2][2], bv[2][2];
#pragma unroll
        for (int rr = 0; rr < 2; ++rr) {
          int row = rr * 64 + srow;
          const u32x4* bp = (const u32x4*)(Bt + (size_t)(ng * 128 + row) * 1024 + kt * 64 + qd * 16);
          bv[rr][0] = bp[0]; bv[rr][1] = bp[1];
          int rg = 512 * c + mg * 128 + row;
          if (IS2) {
            // h1 from hpub1 ring: slot t=rg>>5, batch b=rg&31, k-pack p=kt*8+qd*2
            int tq = rg >> 5, b2 = rg & 31;
            int p = kt * 8 + qd * 2;
            const char* ap = (const char*)Ahp + (size_t)tq * 65536 +
                             (size_t)(p * 32 + b2) * 16;
            asm volatile("global_load_dwordx4 %0, %1, off sc0 sc1"
                         : "=v"(aw[rr][0]) : "v"(ap) : "memory");
            asm volatile("global_load_dwordx4 %0, %1, off sc0 sc1"
                         : "=v"(aw[rr][1]) : "v"(ap + 512) : "memory");
          } else {
            const f32x4* ap = (const f32x4*)(Af32 +
                ((size_t)(rg & 31) * 256 + (rg >> 5)) * 1024 + kt * 64 + qd * 16);
            f32x4 a0 = ap[0], a1 = ap[1], a2 = ap[2], a3 = ap[3];
            aw[rr][0][0] = pk2(a0[0], a0[1]); aw[rr][0][1] = pk2(a0[2], a0[3]);
            aw[rr][0][2] = pk2(a1[0], a1[1]); aw[rr][0][3] = pk2(a1[2], a1[3]);
            aw[rr][1][0] = pk2(a2[0], a2[1]); aw[rr][1][1] = pk2(a2[2], a2[3]);
            aw[rr][1][2] = pk2(a3[0], a3[1]); aw[rr][1][3] = pk2(a3[2], a3[3]);
          }
        }
        __syncthreads();  // previous MFMA reads done before overwrite
        if (IS2) {
          asm volatile("s_waitcnt vmcnt(0)" ::: "memory");  // asm loads landed
          __builtin_amdgcn_sched_barrier(0);
        }
#pragma unroll
        for (int rr = 0; rr < 2; ++rr) {
          int row = rr * 64 + srow;
          u32 sw = (u32)((row & 7) << 4);
          int base = row * 128 + qd * 32;
          *(u32x4*)((char*)As + ((base) ^ sw)) = aw[rr][0];
          *(u32x4*)((char*)As + ((base + 16) ^ sw)) = aw[rr][1];
          *(u32x4*)((char*)Bs + ((base) ^ sw)) = bv[rr][0];
          *(u32x4*)((char*)Bs + ((base + 16) ^ sw)) = bv[rr][1];
        }
        __syncthreads();
#pragma unroll
        for (int k2 = 0; k2 < 2; ++k2) {
          short8 af[4], bf[4];
#pragma unroll
          for (int f = 0; f < 4; ++f) {
            af[f] = *(const short8*)((const char*)As +
                     (((wm * 64 + f * 16 + l15) * 128 + k2 * 64 + lq * 16) ^ rsw));
            bf[f] = *(const short8*)((const char*)Bs +
                     (((wn * 64 + f * 16 + l15) * 128 + k2 * 64 + lq * 16) ^ rsw));
          }
#pragma unroll
          for (int fi = 0; fi < 4; ++fi)
#pragma unroll
            for (int fj = 0; fj < 4; ++fj)
              acc[fi][fj] = MFMA16(af[fi], bf[fj], acc[fi][fj]);
        }
      }
      // ---- epilogue: +bias, store bf16 to ring slot c&3 (uncached) ----
#pragma unroll
      for (int fj = 0; fj < 4; ++fj) {
        int gc = ng * 128 + wn * 64 + fj * 16 + l15;
        float bvv = bias[permcol(gc)];
#pragma unroll
        for (int fi = 0; fi < 4; ++fi) {
          int rr0 = (c & 3) * 512 + mg * 128 + wm * 64 + fi * 16 + lq * 4;
#pragma unroll
          for (int r = 0; r < 4; ++r) {
            u32 vv = (u32)f2bf(acc[fi][fj][r] + bvv);
            const u16* cp = Cring + (size_t)(rr0 + r) * 4096 + gc;
            asm volatile("global_store_short %0, %1, off sc0 sc1"
                         :: "v"(cp), "v"(vv) : "memory");
          }
        }
      }
      __syncthreads();  // LDS safe for next e / chunk
    }
    asm volatile("s_waitcnt vmcnt(0)" ::: "memory");  // stores visible before count
    if (tid == 0)
      __hip_atomic_fetch_add(gdone + c, 1, __ATOMIC_RELAXED, __HIP_MEMORY_SCOPE_AGENT);
  }
}

// -------- scan group (persistent): 64 blocks, 16 units each, K=1024 --------
// hpub = FULL-DEPTH ring (256 slots x 64KB = 16MB): no slot reuse within a
// dispatch -> no fences, no reuse gate terms; all data reads uncached (sc0 sc1),
// so graph replays are safe too. Publish layout [k>>3][b] x 16B.
// 1 block/CU: all 16 h-frag loads issued then ONE vmcnt drain (single round trip).
template <int L>
__device__ void scan_grp(char* smem, int nb,
    const u16* __restrict__ xpring, const u16* __restrict__ Wt,
    const int* __restrict__ lengths, u64* hpub,
    int* flags_self, const int* gdone,
    float* __restrict__ outp, float* __restrict__ csf, float* __restrict__ hsf) {
  f32x4* partv = (f32x4*)smem;                   // 32KB
  u16* h_stage = (u16*)(smem + 32768);           // 1KB  [b][16u]
  float* out_stage = (float*)(smem + 33792);     // 2KB  [b][16u] (L=1)
  const int tid = threadIdx.x;
  const int lane = tid & 63, w = tid >> 6;
  const int l15 = lane & 15, q = lane >> 4;
  const int b = (w & 1) * 16 + l15;
  const int u0 = (w >> 1) * 4 + q;  // 0..7; second unit = u0+8
  const int len = lengths[b];

  // Wh A-fragments register-resident: 32 x short8 = 128 VGPR
  short8 afr[4][8];
#pragma unroll
  for (int tt = 0; tt < 4; ++tt)
#pragma unroll
    for (int ks = 0; ks < 8; ++ks)
      afr[tt][ks] = *(const short8*)(Wt + (size_t)(nb * 64 + tt * 16 + l15) * 1024 +
                                     w * 256 + ks * 32 + q * 8);

  f32x4 acc[4][2];
#pragma unroll
  for (int tt = 0; tt < 4; ++tt)
#pragma unroll
    for (int bc = 0; bc < 2; ++bc) acc[tt][bc] = (f32x4){0.f, 0.f, 0.f, 0.f};
  float c0 = 0.f, h0 = 0.f, c1 = 0.f, h1 = 0.f;

  for (int t = 0; t < 256; ++t) {
    // ---- gate: peers >= t, xp chunk ready ----
    if (w == 0) {
      const int cidx = t >> 4;
      while (1) {
        bool ok = true;
        if (lane < 16) {
          u32x4 fv;
          const u32x4* fp = (const u32x4*)flags_self + lane;
          asm volatile("global_load_dwordx4 %0, %1, off sc0 sc1"
                       : "=v"(fv) : "v"(fp) : "memory");
          asm volatile("s_waitcnt vmcnt(0)" ::: "memory");
          ok = (int)fv[0] >= t && (int)fv[1] >= t && (int)fv[2] >= t && (int)fv[3] >= t;
        } else if (lane == 16) {
          u32 cd;
          const int* gp = gdone + cidx;
          asm volatile("global_load_dword %0, %1, off sc0 sc1"
                       : "=v"(cd) : "v"(gp) : "memory");
          asm volatile("s_waitcnt vmcnt(0)" ::: "memory");
          ok = (int)cd >= 64;
        }
        if (__all(ok)) break;
        __builtin_amdgcn_s_sleep(1);
      }
    }
    __syncthreads();  // BP

    // ---- xp loads (uncached; ring slot (t>>4)&3, row (t&15)*32+b), 2 units ----
    const u16* xa = xpring + ((size_t)((t >> 4) & 3) * 512 + (t & 15) * 32 + b) * 4096 +
                    nb * 64 + u0 * 4;
    u32x2 xpv0, xpv1;
    asm volatile("global_load_dwordx2 %0, %1, off sc0 sc1"
                 : "=v"(xpv0) : "v"(xa) : "memory");
    asm volatile("global_load_dwordx2 %0, %1, off sc0 sc1"
                 : "=v"(xpv1) : "v"(xa + 32) : "memory");

    // ---- h fragments: all 16 issued, ONE drain, then 64 MFMA ----
    if (t > 0) {
      const char* hp = (const char*)hpub + (size_t)(t - 1) * 65536;
      short8 bfv[16];
#pragma unroll
      for (int i = 0; i < 16; ++i) {
        const int ks = i >> 1, bc = i & 1;
        const char* p = hp + (((w * 32 + ks * 4 + q) * 32 + bc * 16 + l15) << 4);
        asm volatile("global_load_dwordx4 %0, %1, off sc0 sc1"
                     : "=v"(bfv[i]) : "v"(p) : "memory");
      }
      asm volatile("s_waitcnt vmcnt(0)" ::: "memory");
      __builtin_amdgcn_sched_barrier(0);
#pragma unroll
      for (int i = 0; i < 16; ++i) {
        const int ks = i >> 1, bc = i & 1;
        acc[0][bc] = MFMA16(afr[0][ks], bfv[i], acc[0][bc]);
        acc[1][bc] = MFMA16(afr[1][ks], bfv[i], acc[1][bc]);
        acc[2][bc] = MFMA16(afr[2][ks], bfv[i], acc[2][bc]);
        acc[3][bc] = MFMA16(afr[3][ks], bfv[i], acc[3][bc]);
      }
    } else {
      asm volatile("s_waitcnt vmcnt(0)" ::: "memory");
      __builtin_amdgcn_sched_barrier(0);
    }

    // ---- cross-wave K reduction (8 combos, 32 slots) ----
#pragma unroll
    for (int tt = 0; tt < 4; ++tt)
#pragma unroll
      for (int bc = 0; bc < 2; ++bc) {
        partv[(w * 8 + tt * 2 + bc) * 64 + lane] = acc[tt][bc];
        acc[tt][bc] = (f32x4){0.f, 0.f, 0.f, 0.f};
      }
    __syncthreads();  // B1
    f32x4 s0 = (f32x4){0.f, 0.f, 0.f, 0.f};
    f32x4 s1 = (f32x4){0.f, 0.f, 0.f, 0.f};
#pragma unroll
    for (int w2 = 0; w2 < 4; ++w2) {
      s0 += partv[(w2 * 8 + w) * 64 + lane];       // combo w   -> unit u0
      s1 += partv[(w2 * 8 + 4 + w) * 64 + lane];   // combo w+4 -> unit u0+8
    }

    bool mk = t < len;
    {
      float zi = s0[0] + bf2f((u16)(xpv0[0] & 0xffffu));
      float zj = s0[1] + bf2f((u16)(xpv0[0] >> 16));
      float zf = s0[2] + bf2f((u16)(xpv0[1] & 0xffffu)) + 1.f;  // FORGET_BIAS
      float zo = s0[3] + bf2f((u16)(xpv0[1] >> 16));
      float cn = sigm(zf) * c0 + sigm(zi) * tanh_(zj);
      float hn = sigm(zo) * tanh_(cn);
      c0 = mk ? cn : c0;
      h0 = mk ? hn : h0;
      float ov = mk ? hn : 0.f;
      h_stage[b * 16 + u0] = f2bf(ov);
      if (L) out_stage[b * 16 + u0] = ov;
    }
    {
      float zi = s1[0] + bf2f((u16)(xpv1[0] & 0xffffu));
      float zj = s1[1] + bf2f((u16)(xpv1[0] >> 16));
      float zf = s1[2] + bf2f((u16)(xpv1[1] & 0xffffu)) + 1.f;
      float zo = s1[3] + bf2f((u16)(xpv1[1] >> 16));
      float cn = sigm(zf) * c1 + sigm(zi) * tanh_(zj);
      float hn = sigm(zo) * tanh_(cn);
      c1 = mk ? cn : c1;
      h1 = mk ? hn : h1;
      float ov = mk ? hn : 0.f;
      h_stage[b * 16 + u0 + 8] = f2bf(ov);
      if (L) out_stage[b * 16 + u0 + 8] = ov;
    }
    __syncthreads();  // B2

    // ---- publish (uncached), drain, flag ----
    if (tid < 64) {  // 2 k-packs x 32 batches x 16B
      int p = tid >> 5, bb = tid & 31;
      const u64* hsrc = (const u64*)h_stage;
      u64 v0 = hsrc[bb * 4 + p * 2], v1 = hsrc[bb * 4 + p * 2 + 1];
      u64* hd = hpub + (size_t)t * 8192 + ((size_t)((nb * 2 + p) * 32 + bb)) * 2;
      __hip_atomic_store(hd, v0, __ATOMIC_RELAXED, __HIP_MEMORY_SCOPE_AGENT);
      __hip_atomic_store(hd + 1, v1, __ATOMIC_RELAXED, __HIP_MEMORY_SCOPE_AGENT);
    }
    asm volatile("s_waitcnt vmcnt(0)" ::: "memory");  // visible before flag
    if (tid == 0)
      __hip_atomic_store(flags_self + nb, t + 1, __ATOMIC_RELAXED,
                         __HIP_MEMORY_SCOPE_AGENT);
    if (L && tid < 128) {  // rnnout rows (b, t), 16 cols
      int bb = tid >> 2, part = tid & 3;
      f32x4 ov = *(const f32x4*)(out_stage + bb * 16 + part * 4);
      *(f32x4*)(outp + ((size_t)bb * 256 + t) * 1024 + nb * 16 + part * 4) = ov;
    }
  }
  csf[L * 32768 + b * 1024 + nb * 16 + u0] = c0;
  csf[L * 32768 + b * 1024 + nb * 16 + u0 + 8] = c1;
  hsf[L * 32768 + b * 1024 + nb * 16 + u0] = h0;
  hsf[L * 32768 + b * 1024 + nb * 16 + u0 + 8] = h1;
}

// -------- persistent pipeline: G1 64 | scan1 64 | G2 64 | scan2 64, 1 block/CU --------
__global__ __launch_bounds__(256, 1) void lstm_pipe(
    const float* __restrict__ x, const int* __restrict__ lengths,
    const float* __restrict__ bias,
    const u16* __restrict__ WxT1, const u16* __restrict__ WxT2,
    const u16* __restrict__ WhT1, const u16* __restrict__ WhT2,
    u16* xp1ring, u16* xp2ring,
    u64* hpub1, u64* hpub2, int* flags, float* outp) {
  __shared__ __align__(16) char smem[35840];
  int* g1done = flags + 128;
  int* g2done = flags + 144;
  const int bid = blockIdx.x;
  float* csf = outp + RN_;
  float* hsf = csf + 65536;
  if (bid < 64)
    gemm_grp<0>(smem, bid, x, nullptr, WxT1, bias, xp1ring, flags, g1done);
  else if (bid < 128)
    scan_grp<0>(smem, bid - 64, xp1ring, WhT1, lengths, hpub1, flags, g1done,
                outp, csf, hsf);
  else if (bid < 192)
    gemm_grp<1>(smem, bid - 128, nullptr, (const u16*)hpub1, WxT2, bias + 4096,
                xp2ring, flags, g2done);
  else
    scan_grp<1>(smem, bid - 192, xp2ring, WhT2, lengths, hpub2, flags + 64, g2done,
                outp, csf, hsf);
}

// -------- workspace layout (96MB + flags; proven budget) --------
#define WS_WXT1 0u
#define WS_WXT2 (8u << 20)
#define WS_WHT1 (16u << 20)
#define WS_WHT2 (24u << 20)
#define WS_XP1 (32u << 20)    // 4 slots x 512 rows x 4096 x 2B = 16MB
#define WS_XP2 (48u << 20)    // 16MB
#define WS_HPUB1 (64u << 20)  // 256 slots x 64KB = 16MB (full depth)
#define WS_HPUB2 (80u << 20)  // 16MB
#define WS_FLAGS (96u << 20)  // 128 scan flags + 2x16 chunk counters

extern "C" void kernel_launch(void* const* d_in, const int* in_sizes, int n_in,
                              void* d_out, int out_size, void* d_ws, size_t ws_size,
                              hipStream_t stream) {
  const float* x = (const float*)d_in[0];
  const int* lengths = (const int*)d_in[1];
  const float* Wx = (const float*)d_in[2];
  const float* Wh = (const float*)d_in[3];
  const float* bias = (const float*)d_in[4];
  float* outp = (float*)d_out;

  if (ws_size < (size_t)WS_FLAGS + 4096) return;  // fail loudly (output stays poison)

  char* ws = (char*)d_ws;
  u16* WxT1 = (u16*)(ws + WS_WXT1);
  u16* WxT2 = (u16*)(ws + WS_WXT2);
  u16* WhT1 = (u16*)(ws + WS_WHT1);
  u16* WhT2 = (u16*)(ws + WS_WHT2);
  u16* xp1ring = (u16*)(ws + WS_XP1);
  u16* xp2ring = (u16*)(ws + WS_XP2);
  u64* hpub1 = (u64*)(ws + WS_HPUB1);
  u64* hpub2 = (u64*)(ws + WS_HPUB2);
  int* flags = (int*)(ws + WS_FLAGS);

  hipMemsetAsync(flags, 0, 2048, stream);
  transpose_convert<<<4096, 256, 0, stream>>>(Wx, Wh, WxT1, WxT2, WhT1, WhT2);
  lstm_pipe<<<256, 256, 0, stream>>>(x, lengths, bias, WxT1, WxT2, WhT1, WhT2,
                                     xp1ring, xp2ring, hpub1, hpub2, flags, outp);
}

// Round 9
// 1231.634 us; speedup vs baseline: 1.6198x; 1.0301x over previous
//
#include <hip/hip_runtime.h>

typedef unsigned short u16;
typedef unsigned int u32;
typedef unsigned long long u64;
typedef __attribute__((ext_vector_type(8))) short short8;
typedef __attribute__((ext_vector_type(4))) float f32x4;
typedef __attribute__((ext_vector_type(4))) u32 u32x4;
typedef __attribute__((ext_vector_type(2))) u32 u32x2;

#define RN_ 8388608  // B*T*H
#define MFMA16(a, b, c) __builtin_amdgcn_mfma_f32_16x16x32_bf16(a, b, c, 0, 0, 0)

__device__ __forceinline__ u16 f2bf(float f) {
  union { float f; u32 u; } v; v.f = f;
  u32 r = v.u + 0x7fffu + ((v.u >> 16) & 1u);  // RNE (inputs finite)
  return (u16)(r >> 16);
}
__device__ __forceinline__ float bf2f(u16 h) {
  union { u32 u; float f; } v; v.u = ((u32)h) << 16;
  return v.f;
}
__device__ __forceinline__ u32 pk2(float a, float b) {
  return (u32)f2bf(a) | ((u32)f2bf(b) << 16);
}
// scan column ordering (absolute R in [0,4096)):
// R = (k>>3 block of 8 units)*32 + (u&7)*4 + gate  ->  original g = gate*1024 + unit
__device__ __forceinline__ int permcol(int R) {
  return (R & 3) * 1024 + ((R >> 5) << 3) + ((R >> 2) & 7);
}
__device__ __forceinline__ float sigm(float x) { return 1.f / (1.f + __expf(-x)); }
__device__ __forceinline__ float tanh_(float x) {
  float e = __expf(2.f * x);
  return 1.f - 2.f / (e + 1.f);
}

// -------- transpose + convert + permute: four [4096][1024] bf16 buffers --------
__global__ __launch_bounds__(256) void transpose_convert(
    const float* __restrict__ Wx, const float* __restrict__ Wh,
    u16* __restrict__ WxT1, u16* __restrict__ WxT2,
    u16* __restrict__ WhT1, u16* __restrict__ WhT2) {
  __shared__ float lds[64][65];
  const int bid = blockIdx.x, tid = threadIdx.x;
  const int sel = bid >> 10;
  const int tile = bid & 1023;
  const int kt = tile & 15, rt = tile >> 4;  // 16 k-tiles x 64 R-tiles
  const float* src;
  u16* dst;
  if (sel == 0)      { src = Wx;                       dst = WxT1; }
  else if (sel == 1) { src = Wx + (size_t)1024 * 4096; dst = WxT2; }
  else if (sel == 2) { src = Wh;                       dst = WhT1; }
  else               { src = Wh + (size_t)1024 * 4096; dst = WhT2; }
#pragma unroll
  for (int ii = 0; ii < 16; ++ii) {
    int idx = ii * 256 + tid;
    int r = idx >> 6, c = idx & 63;
    int run = c >> 3, u = c & 7;
    int blkLoc = run >> 2, gate = run & 3;
    int g = gate * 1024 + (rt * 2 + blkLoc) * 8 + u;
    lds[r][blkLoc * 32 + u * 4 + gate] = src[(size_t)(kt * 64 + r) * 4096 + g];
  }
  __syncthreads();
#pragma unroll
  for (int ii = 0; ii < 16; ++ii) {
    int idx = ii * 256 + tid;
    int rw = idx >> 6, cw = idx & 63;
    dst[(size_t)(rt * 64 + rw) * 1024 + kt * 64 + cw] = f2bf(lds[cw][rw]);
  }
}

// -------- chunked GEMM group (persistent): 64 blocks, 16 chunks, 2 tiles/chunk --------
// IS2=0: A = x (f32, rows remapped b*256+t), out -> xp1ring; gate: xp1 ring reuse.
// IS2=1: A = h1 read DIRECTLY from full-depth hpub1 ring (uncached); gate: scan1
//        chunk published + xp2 ring reuse vs scan2.
// C rows t-major (r = t*32+b), cols permuted; bias added here. C stores uncached.
// flags layout: [0..63] scan1, [64..127] scan2 (updated once per 16-step chunk).
template <int IS2>
__device__ void gemm_grp(char* smem, int gb,
    const float* __restrict__ Af32, const u16* __restrict__ Ahp,
    const u16* __restrict__ Bt, const float* __restrict__ bias,
    u16* __restrict__ Cring, const int* flags, int* gdone) {
  u16* As = (u16*)smem;
  u16* Bs = (u16*)(smem + 16384);
  const int tid = threadIdx.x;
  const int lane = tid & 63, w = tid >> 6;
  const int wm = w >> 1, wn = w & 1;
  const int l15 = lane & 15, lq = lane >> 4;
  const int srow = tid >> 2, qd = tid & 3;
  const u32 rsw = (u32)((l15 & 7) << 4);

  for (int c = 0; c < 16; ++c) {
    // ---- gate (once per chunk) ----
    if (w == 0) {
      const int thrA = IS2 ? 16 * (c + 1) : 16 * c - 48;  // scan1 flags
      const int thrB = 16 * c - 48;                        // scan2 flags (xp2 reuse)
      while (1) {
        bool ok = true;
        if (lane < 16) {
          u32x4 fv;
          const u32x4* fp = (const u32x4*)flags + lane;
          asm volatile("global_load_dwordx4 %0, %1, off sc0 sc1"
                       : "=v"(fv) : "v"(fp) : "memory");
          asm volatile("s_waitcnt vmcnt(0)" ::: "memory");
          __builtin_amdgcn_sched_barrier(0);
          ok = (int)fv[0] >= thrA && (int)fv[1] >= thrA &&
               (int)fv[2] >= thrA && (int)fv[3] >= thrA;
        } else if (IS2 && lane < 32) {
          u32x4 fv;
          const u32x4* fp = (const u32x4*)(flags + 64) + (lane - 16);
          asm volatile("global_load_dwordx4 %0, %1, off sc0 sc1"
                       : "=v"(fv) : "v"(fp) : "memory");
          asm volatile("s_waitcnt vmcnt(0)" ::: "memory");
          __builtin_amdgcn_sched_barrier(0);
          ok = (int)fv[0] >= thrB && (int)fv[1] >= thrB &&
               (int)fv[2] >= thrB && (int)fv[3] >= thrB;
        }
        if (__all(ok)) break;
        __builtin_amdgcn_s_sleep(8);
      }
    }
    __syncthreads();

    for (int e = 0; e < 2; ++e) {  // 2 tiles per block per chunk
      const int ti = gb * 2 + e;
      const int mg = ti >> 5, ng = ti & 31;

      f32x4 acc[4][4];
#pragma unroll
      for (int i = 0; i < 4; ++i)
#pragma unroll
        for (int j = 0; j < 4; ++j) acc[i][j] = (f32x4){0.f, 0.f, 0.f, 0.f};

      for (int kt = 0; kt < 16; ++kt) {
        u32x4 aw[2][2], bv[2][2];
#pragma unroll
        for (int rr = 0; rr < 2; ++rr) {
          int row = rr * 64 + srow;
          const u32x4* bp = (const u32x4*)(Bt + (size_t)(ng * 128 + row) * 1024 + kt * 64 + qd * 16);
          bv[rr][0] = bp[0]; bv[rr][1] = bp[1];
          int rg = 512 * c + mg * 128 + row;
          if (IS2) {
            // h1 from hpub1 ring: slot t=rg>>5, batch b=rg&31, k-pack p=kt*8+qd*2
            int tq = rg >> 5, b2 = rg & 31;
            int p = kt * 8 + qd * 2;
            const char* ap = (const char*)Ahp + (size_t)tq * 65536 +
                             (size_t)(p * 32 + b2) * 16;
            asm volatile("global_load_dwordx4 %0, %1, off sc0 sc1"
                         : "=v"(aw[rr][0]) : "v"(ap) : "memory");
            asm volatile("global_load_dwordx4 %0, %1, off sc0 sc1"
                         : "=v"(aw[rr][1]) : "v"(ap + 512) : "memory");
          } else {
            const f32x4* ap = (const f32x4*)(Af32 +
                ((size_t)(rg & 31) * 256 + (rg >> 5)) * 1024 + kt * 64 + qd * 16);
            f32x4 a0 = ap[0], a1 = ap[1], a2 = ap[2], a3 = ap[3];
            aw[rr][0][0] = pk2(a0[0], a0[1]); aw[rr][0][1] = pk2(a0[2], a0[3]);
            aw[rr][0][2] = pk2(a1[0], a1[1]); aw[rr][0][3] = pk2(a1[2], a1[3]);
            aw[rr][1][0] = pk2(a2[0], a2[1]); aw[rr][1][1] = pk2(a2[2], a2[3]);
            aw[rr][1][2] = pk2(a3[0], a3[1]); aw[rr][1][3] = pk2(a3[2], a3[3]);
          }
        }
        __syncthreads();  // previous MFMA reads done before overwrite
        if (IS2) {
          asm volatile("s_waitcnt vmcnt(0)" ::: "memory");  // asm loads landed
          __builtin_amdgcn_sched_barrier(0);
        }
#pragma unroll
        for (int rr = 0; rr < 2; ++rr) {
          int row = rr * 64 + srow;
          u32 sw = (u32)((row & 7) << 4);
          int base = row * 128 + qd * 32;
          *(u32x4*)((char*)As + ((base) ^ sw)) = aw[rr][0];
          *(u32x4*)((char*)As + ((base + 16) ^ sw)) = aw[rr][1];
          *(u32x4*)((char*)Bs + ((base) ^ sw)) = bv[rr][0];
          *(u32x4*)((char*)Bs + ((base + 16) ^ sw)) = bv[rr][1];
        }
        __syncthreads();
#pragma unroll
        for (int k2 = 0; k2 < 2; ++k2) {
          short8 af[4], bf[4];
#pragma unroll
          for (int f = 0; f < 4; ++f) {
            af[f] = *(const short8*)((const char*)As +
                     (((wm * 64 + f * 16 + l15) * 128 + k2 * 64 + lq * 16) ^ rsw));
            bf[f] = *(const short8*)((const char*)Bs +
                     (((wn * 64 + f * 16 + l15) * 128 + k2 * 64 + lq * 16) ^ rsw));
          }
#pragma unroll
          for (int fi = 0; fi < 4; ++fi)
#pragma unroll
            for (int fj = 0; fj < 4; ++fj)
              acc[fi][fj] = MFMA16(af[fi], bf[fj], acc[fi][fj]);
        }
      }
      // ---- epilogue: +bias, store bf16 to ring slot c&3 (uncached) ----
#pragma unroll
      for (int fj = 0; fj < 4; ++fj) {
        int gc = ng * 128 + wn * 64 + fj * 16 + l15;
        float bvv = bias[permcol(gc)];
#pragma unroll
        for (int fi = 0; fi < 4; ++fi) {
          int rr0 = (c & 3) * 512 + mg * 128 + wm * 64 + fi * 16 + lq * 4;
#pragma unroll
          for (int r = 0; r < 4; ++r) {
            u32 vv = (u32)f2bf(acc[fi][fj][r] + bvv);
            const u16* cp = Cring + (size_t)(rr0 + r) * 4096 + gc;
            asm volatile("global_store_short %0, %1, off sc0 sc1"
                         :: "v"(cp), "v"(vv) : "memory");
          }
        }
      }
      __syncthreads();  // LDS safe for next e / chunk
    }
    asm volatile("s_waitcnt vmcnt(0)" ::: "memory");  // stores visible before count
    if (tid == 0)
      __hip_atomic_fetch_add(gdone + c, 1, __ATOMIC_RELAXED, __HIP_MEMORY_SCOPE_AGENT);
  }
}

// -------- scan group (persistent): 64 blocks, 16 units each, K=1024 --------
// hpub = FULL-DEPTH poisoned ring (256 slots x 64KB, memset 0xFF per launch):
// a dword == 0xFFFFFFFF (2x bf16 NaN) marks stale; published h is finite, so
// consumers DATA-POLL (no flags on the critical path). Producer publish is
// fire-and-forget dwordx4 (no drain). Scan progress flags are published once
// per 16-step chunk (after a wave-0 drain) for the GEMM groups' chunk gates.
// xp chunk gate checked at chunk boundaries only (monotone within a chunk).
template <int L>
__device__ void scan_grp(char* smem, int nb,
    const u16* __restrict__ xpring, const u16* __restrict__ Wt,
    const int* __restrict__ lengths, u64* hpub,
    int* flags_self, const int* gdone,
    float* __restrict__ outp, float* __restrict__ csf, float* __restrict__ hsf) {
  f32x4* partv = (f32x4*)smem;                   // 32KB
  u16* h_stage = (u16*)(smem + 32768);           // 1KB  [b][16u]
  float* out_stage = (float*)(smem + 33792);     // 2KB  [b][16u] (L=1)
  const int tid = threadIdx.x;
  const int lane = tid & 63, w = tid >> 6;
  const int l15 = lane & 15, q = lane >> 4;
  const int b = (w & 1) * 16 + l15;
  const int u0 = (w >> 1) * 4 + q;  // 0..7; second unit = u0+8
  const int len = lengths[b];

  // Wh A-fragments register-resident: 32 x short8 = 128 VGPR
  short8 afr[4][8];
#pragma unroll
  for (int tt = 0; tt < 4; ++tt)
#pragma unroll
    for (int ks = 0; ks < 8; ++ks)
      afr[tt][ks] = *(const short8*)(Wt + (size_t)(nb * 64 + tt * 16 + l15) * 1024 +
                                     w * 256 + ks * 32 + q * 8);

  f32x4 acc[4][2];
#pragma unroll
  for (int tt = 0; tt < 4; ++tt)
#pragma unroll
    for (int bc = 0; bc < 2; ++bc) acc[tt][bc] = (f32x4){0.f, 0.f, 0.f, 0.f};
  float c0 = 0.f, h0 = 0.f, c1 = 0.f, h1 = 0.f;

  for (int t = 0; t < 256; ++t) {
    // ---- chunk boundary: xp-chunk gate (1 in 16 steps) ----
    if ((t & 15) == 0) {
      if (w == 0) {
        const int cidx = t >> 4;
        while (1) {
          bool ok = true;
          if (lane == 0) {
            u32 cd;
            asm volatile("global_load_dword %0, %1, off sc0 sc1"
                         : "=v"(cd) : "v"(gdone + cidx) : "memory");
            asm volatile("s_waitcnt vmcnt(0)" ::: "memory");
            __builtin_amdgcn_sched_barrier(0);
            ok = (int)cd >= 64;
          }
          if (__all(ok)) break;
          __builtin_amdgcn_s_sleep(2);
        }
      }
      __syncthreads();
    }

    // ---- xp loads (uncached; ring slot (t>>4)&3, row (t&15)*32+b), 2 units ----
    const u16* xa = xpring + ((size_t)((t >> 4) & 3) * 512 + (t & 15) * 32 + b) * 4096 +
                    nb * 64 + u0 * 4;
    u32x2 xpv0, xpv1;
    asm volatile("global_load_dwordx2 %0, %1, off sc0 sc1"
                 : "=v"(xpv0) : "v"(xa) : "memory");
    asm volatile("global_load_dwordx2 %0, %1, off sc0 sc1"
                 : "=v"(xpv1) : "v"(xa + 32) : "memory");

    // ---- h fragments: DATA-POLL (retry until no poison), then 64 MFMA ----
    if (t > 0) {
      const char* hp = (const char*)hpub + (size_t)(t - 1) * 65536;
      short8 bfv[16];
      while (1) {
#pragma unroll
        for (int i = 0; i < 16; ++i) {
          const int ks = i >> 1, bc = i & 1;
          const char* p = hp + (((w * 32 + ks * 4 + q) * 32 + bc * 16 + l15) << 4);
          asm volatile("global_load_dwordx4 %0, %1, off sc0 sc1"
                       : "=v"(bfv[i]) : "v"(p) : "memory");
        }
        asm volatile("s_waitcnt vmcnt(0)" ::: "memory");
        __builtin_amdgcn_sched_barrier(0);
        bool ok = true;
#pragma unroll
        for (int i = 0; i < 16; ++i) {
          u32x4 vv = __builtin_bit_cast(u32x4, bfv[i]);
          ok = ok && (vv[0] != 0xFFFFFFFFu) && (vv[1] != 0xFFFFFFFFu) &&
               (vv[2] != 0xFFFFFFFFu) && (vv[3] != 0xFFFFFFFFu);
        }
        if (__all(ok)) break;
        __builtin_amdgcn_s_sleep(1);
      }
      __builtin_amdgcn_sched_barrier(0);
#pragma unroll
      for (int i = 0; i < 16; ++i) {
        const int ks = i >> 1, bc = i & 1;
        acc[0][bc] = MFMA16(afr[0][ks], bfv[i], acc[0][bc]);
        acc[1][bc] = MFMA16(afr[1][ks], bfv[i], acc[1][bc]);
        acc[2][bc] = MFMA16(afr[2][ks], bfv[i], acc[2][bc]);
        acc[3][bc] = MFMA16(afr[3][ks], bfv[i], acc[3][bc]);
      }
    } else {
      asm volatile("s_waitcnt vmcnt(0)" ::: "memory");
      __builtin_amdgcn_sched_barrier(0);
    }

    // ---- cross-wave K reduction (8 combos, 32 slots) ----
#pragma unroll
    for (int tt = 0; tt < 4; ++tt)
#pragma unroll
      for (int bc = 0; bc < 2; ++bc) {
        partv[(w * 8 + tt * 2 + bc) * 64 + lane] = acc[tt][bc];
        acc[tt][bc] = (f32x4){0.f, 0.f, 0.f, 0.f};
      }
    __syncthreads();  // B1
    f32x4 s0 = (f32x4){0.f, 0.f, 0.f, 0.f};
    f32x4 s1 = (f32x4){0.f, 0.f, 0.f, 0.f};
#pragma unroll
    for (int w2 = 0; w2 < 4; ++w2) {
      s0 += partv[(w2 * 8 + w) * 64 + lane];       // combo w   -> unit u0
      s1 += partv[(w2 * 8 + 4 + w) * 64 + lane];   // combo w+4 -> unit u0+8
    }

    bool mk = t < len;
    {
      float zi = s0[0] + bf2f((u16)(xpv0[0] & 0xffffu));
      float zj = s0[1] + bf2f((u16)(xpv0[0] >> 16));
      float zf = s0[2] + bf2f((u16)(xpv0[1] & 0xffffu)) + 1.f;  // FORGET_BIAS
      float zo = s0[3] + bf2f((u16)(xpv0[1] >> 16));
      float cn = sigm(zf) * c0 + sigm(zi) * tanh_(zj);
      float hn = sigm(zo) * tanh_(cn);
      c0 = mk ? cn : c0;
      h0 = mk ? hn : h0;
      float ov = mk ? hn : 0.f;
      h_stage[b * 16 + u0] = f2bf(ov);
      if (L) out_stage[b * 16 + u0] = ov;
    }
    {
      float zi = s1[0] + bf2f((u16)(xpv1[0] & 0xffffu));
      float zj = s1[1] + bf2f((u16)(xpv1[0] >> 16));
      float zf = s1[2] + bf2f((u16)(xpv1[1] & 0xffffu)) + 1.f;
      float zo = s1[3] + bf2f((u16)(xpv1[1] >> 16));
      float cn = sigm(zf) * c1 + sigm(zi) * tanh_(zj);
      float hn = sigm(zo) * tanh_(cn);
      c1 = mk ? cn : c1;
      h1 = mk ? hn : h1;
      float ov = mk ? hn : 0.f;
      h_stage[b * 16 + u0 + 8] = f2bf(ov);
      if (L) out_stage[b * 16 + u0 + 8] = ov;
    }
    __syncthreads();  // B2 (h_stage complete)

    // ---- publish: fire-and-forget 16B stores (wave 0) ----
    if (tid < 64) {  // 2 k-packs x 32 batches x 16B
      int p = tid >> 5, bb = tid & 31;
      u32x4 pv = *(const u32x4*)((const char*)h_stage + bb * 32 + p * 16);
      char* hd = (char*)hpub + (size_t)t * 65536 +
                 (size_t)((nb * 2 + p) * 32 + bb) * 16;
      asm volatile("global_store_dwordx4 %0, %1, off sc0 sc1"
                   :: "v"(hd), "v"(pv) : "memory");
    }
    // ---- chunk end: drain + progress flag (1 in 16 steps, wave 0 only) ----
    if (((t + 1) & 15) == 0 && w == 0) {
      asm volatile("s_waitcnt vmcnt(0)" ::: "memory");
      if (tid == 0)
        __hip_atomic_store(flags_self + nb, t + 1, __ATOMIC_RELAXED,
                           __HIP_MEMORY_SCOPE_AGENT);
    }
    if (L && tid < 128) {  // rnnout rows (b, t), 16 cols
      int bb = tid >> 2, part = tid & 3;
      f32x4 ov = *(const f32x4*)(out_stage + bb * 16 + part * 4);
      *(f32x4*)(outp + ((size_t)bb * 256 + t) * 1024 + nb * 16 + part * 4) = ov;
    }
  }
  csf[L * 32768 + b * 1024 + nb * 16 + u0] = c0;
  csf[L * 32768 + b * 1024 + nb * 16 + u0 + 8] = c1;
  hsf[L * 32768 + b * 1024 + nb * 16 + u0] = h0;
  hsf[L * 32768 + b * 1024 + nb * 16 + u0 + 8] = h1;
}

// -------- persistent pipeline: G1 64 | scan1 64 | G2 64 | scan2 64, 1 block/CU --------
__global__ __launch_bounds__(256, 1) void lstm_pipe(
    const float* __restrict__ x, const int* __restrict__ lengths,
    const float* __restrict__ bias,
    const u16* __restrict__ WxT1, const u16* __restrict__ WxT2,
    const u16* __restrict__ WhT1, const u16* __restrict__ WhT2,
    u16* xp1ring, u16* xp2ring,
    u64* hpub1, u64* hpub2, int* flags, float* outp) {
  __shared__ __align__(16) char smem[35840];
  int* g1done = flags + 128;
  int* g2done = flags + 144;
  const int bid = blockIdx.x;
  float* csf = outp + RN_;
  float* hsf = csf + 65536;
  if (bid < 64)
    gemm_grp<0>(smem, bid, x, nullptr, WxT1, bias, xp1ring, flags, g1done);
  else if (bid < 128)
    scan_grp<0>(smem, bid - 64, xp1ring, WhT1, lengths, hpub1, flags, g1done,
                outp, csf, hsf);
  else if (bid < 192)
    gemm_grp<1>(smem, bid - 128, nullptr, (const u16*)hpub1, WxT2, bias + 4096,
                xp2ring, flags, g2done);
  else
    scan_grp<1>(smem, bid - 192, xp2ring, WhT2, lengths, hpub2, flags + 64, g2done,
                outp, csf, hsf);
}

// -------- workspace layout (96MB + flags; proven budget) --------
#define WS_WXT1 0u
#define WS_WXT2 (8u << 20)
#define WS_WHT1 (16u << 20)
#define WS_WHT2 (24u << 20)
#define WS_XP1 (32u << 20)    // 4 slots x 512 rows x 4096 x 2B = 16MB
#define WS_XP2 (48u << 20)    // 16MB
#define WS_HPUB1 (64u << 20)  // 256 slots x 64KB = 16MB (full depth, poisoned)
#define WS_HPUB2 (80u << 20)  // 16MB (poisoned)
#define WS_FLAGS (96u << 20)  // 128 scan flags + 2x16 chunk counters

extern "C" void kernel_launch(void* const* d_in, const int* in_sizes, int n_in,
                              void* d_out, int out_size, void* d_ws, size_t ws_size,
                              hipStream_t stream) {
  const float* x = (const float*)d_in[0];
  const int* lengths = (const int*)d_in[1];
  const float* Wx = (const float*)d_in[2];
  const float* Wh = (const float*)d_in[3];
  const float* bias = (const float*)d_in[4];
  float* outp = (float*)d_out;

  if (ws_size < (size_t)WS_FLAGS + 4096) return;  // fail loudly (output stays poison)

  char* ws = (char*)d_ws;
  u16* WxT1 = (u16*)(ws + WS_WXT1);
  u16* WxT2 = (u16*)(ws + WS_WXT2);
  u16* WhT1 = (u16*)(ws + WS_WHT1);
  u16* WhT2 = (u16*)(ws + WS_WHT2);
  u16* xp1ring = (u16*)(ws + WS_XP1);
  u16* xp2ring = (u16*)(ws + WS_XP2);
  u64* hpub1 = (u64*)(ws + WS_HPUB1);
  u64* hpub2 = (u64*)(ws + WS_HPUB2);
  int* flags = (int*)(ws + WS_FLAGS);

  hipMemsetAsync(flags, 0, 2048, stream);
  hipMemsetAsync(hpub1, 0xFF, 32u << 20, stream);  // poison both hpub rings (NaN)
  transpose_convert<<<4096, 256, 0, stream>>>(Wx, Wh, WxT1, WxT2, WhT1, WhT2);
  lstm_pipe<<<256, 256, 0, stream>>>(x, lengths, bias, WxT1, WxT2, WhT1, WhT2,
                                     xp1ring, xp2ring, hpub1, hpub2, flags, outp);
}